// Round 1
// baseline (1123.131 us; speedup 1.0000x reference)
//
#include <hip/hip_runtime.h>
#include <hip/hip_bf16.h>

#define NE 4
#define HD 768
#define F2 384
#define F1 192
#define NT 131072
#define TT 64
#define TILES_PER_E 2048   // NT/TT

typedef __attribute__((ext_vector_type(8))) short bf16x8;
typedef __attribute__((ext_vector_type(4))) float f32x4;
typedef __attribute__((ext_vector_type(4))) unsigned int u32x4;

// workspace layout (bytes)
#define WS_BUCKET_OFF 256
#define WS_GUT_OFF   (WS_BUCKET_OFF + NE*NT*4)        // 2,097,408
#define WS_DNT_OFF   (WS_GUT_OFF + NE*F2*HD*2)        // 4,456,704 ; end ~5.64 MB

__device__ __forceinline__ unsigned short f2bf(float x) {
    unsigned int u = __float_as_uint(x);
    return (unsigned short)((u + 0x7fffu + ((u >> 16) & 1u)) >> 16);
}
__device__ __forceinline__ unsigned int pk2(float a, float b) {
    unsigned int ua = __float_as_uint(a), ub = __float_as_uint(b);
    unsigned int lo = (ua + 0x7fffu + ((ua >> 16) & 1u)) >> 16;
    unsigned int hi = (ub + 0x7fffu + ((ub >> 16) & 1u)) & 0xffff0000u;
    return lo | hi;
}

__global__ void route_kernel(const int* __restrict__ ids, int* __restrict__ counts,
                             int* __restrict__ bucket) {
    int t = blockIdx.x * blockDim.x + threadIdx.x;
    if (t < NT) {
        int e = ids[t];
        int pos = atomicAdd(&counts[e], 1);
        bucket[e * NT + pos] = t;
    }
}

// fp32 -> bf16 with transpose: guT[e][f][k] (k contig), dnT[e][h][f] (f contig)
__global__ void convert_kernel(const float* __restrict__ gu, const float* __restrict__ dn,
                               unsigned short* __restrict__ guT, unsigned short* __restrict__ dnT) {
    int idx = blockIdx.x * blockDim.x + threadIdx.x;
    if (idx < NE * F2 * HD) {
        int k = idx % HD; int r = idx / HD; int f = r % F2; int e = r / F2;
        guT[idx] = f2bf(gu[(e * HD + k) * F2 + f]);
    }
    if (idx < NE * HD * F1) {
        int f = idx % F1; int r = idx / F1; int h = r % HD; int e = r / HD;
        dnT[idx] = f2bf(dn[(e * F1 + f) * HD + h]);
    }
}

__global__ __launch_bounds__(256, 2)
void moe_kernel(const float* __restrict__ hidden, const int* __restrict__ counts,
                const int* __restrict__ bucket, const unsigned short* __restrict__ guT,
                const unsigned short* __restrict__ dnT, float* __restrict__ out)
{
    __shared__ __align__(16) unsigned char smem[41216];
    const int ACT = 8192, TOK = 40960;

    int e = blockIdx.x >> 11;        // / 2048
    int tile = blockIdx.x & 2047;
    int n_e = counts[e];
    int t0 = tile * TT;
    if (t0 >= n_e) return;

    int tid = threadIdx.x;
    int lane = tid & 63;
    int w = tid >> 6;                // wave 0..3
    int lg = lane >> 4;              // lane-group 0..3
    int l16 = lane & 15;

    if (tid < TT) {
        int idx = t0 + tid;
        if (idx >= n_e) idx = n_e - 1;          // duplicate last valid token; store-masked later
        ((int*)(smem + TOK))[tid] = bucket[e * NT + idx];
    }
    __syncthreads();

    // A-staging: thread covers row sr, 16 consecutive k at sq*16
    int sr = tid >> 2, sq = tid & 3;
    const float* srow = hidden + (size_t)(((int*)(smem + TOK))[sr]) * HD + sq * 16;
    int ss = sr & 7;
    unsigned int wb0 = (unsigned int)(sr * 128 + (((sq * 2) ^ ss) << 4));
    unsigned int wb1 = (unsigned int)(sr * 128 + (((sq * 2 + 1) ^ ss) << 4));

    // B1 per-lane byte offsets (gate cols w*48.., up cols 192+w*48.. : in-register pairing)
    const char* guTc = (const char*)(guT + (size_t)e * F2 * HD);
    unsigned int vb1[6];
    #pragma unroll
    for (int nt = 0; nt < 6; ++nt) {
        int col = (nt < 3) ? (w * 48 + nt * 16 + l16) : (192 + w * 48 + (nt - 3) * 16 + l16);
        vb1[nt] = (unsigned int)((col * HD + 8 * lg) * 2);
    }

    const f32x4 fzero = {0.f, 0.f, 0.f, 0.f};
    f32x4 acc[4][6];
    #pragma unroll
    for (int mt = 0; mt < 4; ++mt)
        #pragma unroll
        for (int nt = 0; nt < 6; ++nt) acc[mt][nt] = fzero;

    // ---------------- GEMM1: C1[64][384] over K=768, BK=64 ----------------
    #pragma unroll 1
    for (int k0 = 0; k0 < HD; k0 += 64) {
        if (k0) __syncthreads();
        {
            f32x4 v0 = *(const f32x4*)(srow + k0);
            f32x4 v1 = *(const f32x4*)(srow + k0 + 4);
            f32x4 v2 = *(const f32x4*)(srow + k0 + 8);
            f32x4 v3 = *(const f32x4*)(srow + k0 + 12);
            u32x4 lo = { pk2(v0.x, v0.y), pk2(v0.z, v0.w), pk2(v1.x, v1.y), pk2(v1.z, v1.w) };
            u32x4 hi = { pk2(v2.x, v2.y), pk2(v2.z, v2.w), pk2(v3.x, v3.y), pk2(v3.z, v3.w) };
            *(u32x4*)(smem + wb0) = lo;
            *(u32x4*)(smem + wb1) = hi;
        }
        __syncthreads();

        bf16x8 B[2][6];
        #pragma unroll
        for (int kk = 0; kk < 2; ++kk)
            #pragma unroll
            for (int nt = 0; nt < 6; ++nt)
                B[kk][nt] = *(const bf16x8*)(guTc + (vb1[nt] + (unsigned int)((k0 + kk * 32) * 2)));

        bf16x8 A[2][4];
        #pragma unroll
        for (int kk = 0; kk < 2; ++kk)
            #pragma unroll
            for (int mt = 0; mt < 4; ++mt) {
                int row = mt * 16 + l16;
                unsigned int b = (unsigned int)(row * 128 + (((kk * 4 + lg) ^ (row & 7)) << 4));
                A[kk][mt] = *(const bf16x8*)(smem + b);
            }

        #pragma unroll
        for (int kk = 0; kk < 2; ++kk)
            #pragma unroll
            for (int nt = 0; nt < 6; ++nt)
                #pragma unroll
                for (int mt = 0; mt < 4; ++mt)
                    acc[mt][nt] = __builtin_amdgcn_mfma_f32_16x16x32_bf16(A[kk][mt], B[kk][nt], acc[mt][nt], 0, 0, 0);
    }

    // ---------------- act = silu(gate)*up, in-register pairing, -> swizzled LDS ----------------
    #pragma unroll
    for (int mt = 0; mt < 4; ++mt)
        #pragma unroll
        for (int nt = 0; nt < 3; ++nt)
            #pragma unroll
            for (int p = 0; p < 4; ++p) {
                float g = acc[mt][nt][p];
                float u = acc[mt][nt + 3][p];
                float s = g / (1.f + __expf(-g));
                int row = mt * 16 + 4 * lg + p;
                int f = w * 48 + nt * 16 + l16;
                unsigned int b = (unsigned int)(ACT + row * 512 + (((f >> 3) ^ (row & 7)) << 4) + (f & 7) * 2);
                *(unsigned short*)(smem + b) = f2bf(s * u);
            }
    __syncthreads();

    // ---------------- GEMM2: out[64][768] = act[64][192] * down[192][768] ----------------
    const char* dnTc = (const char*)(dnT + (size_t)e * HD * F1);
    #pragma unroll 1
    for (int half = 0; half < 2; ++half) {
        unsigned int vb2[6];
        #pragma unroll
        for (int nt = 0; nt < 6; ++nt) {
            int h = w * 192 + half * 96 + nt * 16 + l16;
            vb2[nt] = (unsigned int)((h * F1 + 8 * lg) * 2);
        }
        f32x4 c2[4][6];
        #pragma unroll
        for (int mt = 0; mt < 4; ++mt)
            #pragma unroll
            for (int nt = 0; nt < 6; ++nt) c2[mt][nt] = fzero;

        #pragma unroll
        for (int kt = 0; kt < 6; ++kt) {
            bf16x8 A2[4];
            #pragma unroll
            for (int mt = 0; mt < 4; ++mt) {
                int row = mt * 16 + l16;
                unsigned int b = (unsigned int)(ACT + row * 512 + (((kt * 4 + lg) ^ (row & 7)) << 4));
                A2[mt] = *(const bf16x8*)(smem + b);
            }
            bf16x8 B2[6];
            #pragma unroll
            for (int nt = 0; nt < 6; ++nt)
                B2[nt] = *(const bf16x8*)(dnTc + (vb2[nt] + (unsigned int)(kt * 64)));
            #pragma unroll
            for (int nt = 0; nt < 6; ++nt)
                #pragma unroll
                for (int mt = 0; mt < 4; ++mt)
                    c2[mt][nt] = __builtin_amdgcn_mfma_f32_16x16x32_bf16(A2[mt], B2[nt], c2[mt][nt], 0, 0, 0);
        }

        int cb = w * 192 + half * 96 + l16;
        #pragma unroll
        for (int mt = 0; mt < 4; ++mt)
            #pragma unroll
            for (int p = 0; p < 4; ++p) {
                int row = mt * 16 + 4 * lg + p;
                if (t0 + row < n_e) {
                    float* orow = out + (size_t)(((int*)(smem + TOK))[row]) * HD + cb;
                    #pragma unroll
                    for (int nt = 0; nt < 6; ++nt)
                        orow[nt * 16] = c2[mt][nt][p];
                }
            }
    }
}

extern "C" void kernel_launch(void* const* d_in, const int* in_sizes, int n_in,
                              void* d_out, int out_size, void* d_ws, size_t ws_size,
                              hipStream_t stream) {
    (void)in_sizes; (void)n_in; (void)out_size; (void)ws_size;
    const float* hidden = (const float*)d_in[0];
    const int*   ids    = (const int*)d_in[1];
    const float* gu     = (const float*)d_in[2];
    const float* dn     = (const float*)d_in[3];
    float* out = (float*)d_out;

    char* ws = (char*)d_ws;
    int* counts = (int*)ws;
    int* bucket = (int*)(ws + WS_BUCKET_OFF);
    unsigned short* guT = (unsigned short*)(ws + WS_GUT_OFF);
    unsigned short* dnT = (unsigned short*)(ws + WS_DNT_OFF);

    hipMemsetAsync(d_ws, 0, 64, stream);
    route_kernel<<<NT / 256, 256, 0, stream>>>(ids, counts, bucket);
    convert_kernel<<<(NE * F2 * HD + 255) / 256, 256, 0, stream>>>(gu, dn, guT, dnT);
    moe_kernel<<<NE * TILES_PER_E, 256, 0, stream>>>(hidden, counts, bucket, guT, dnT, out);
}

// Round 2
// 419.082 us; speedup vs baseline: 2.6800x; 2.6800x over previous
//
#include <hip/hip_runtime.h>
#include <hip/hip_bf16.h>

#define NE 4
#define HD 768
#define F2 384
#define F1 192
#define NT 131072
#define TT 64
#define TILES_PER_E 2048   // NT/TT

typedef __attribute__((ext_vector_type(8))) short bf16x8;
typedef __attribute__((ext_vector_type(4))) float f32x4;
typedef __attribute__((ext_vector_type(4))) unsigned int u32x4;

// workspace layout (bytes)
#define WS_BUCKET_OFF 256
#define WS_GUT_OFF   (WS_BUCKET_OFF + NE*NT*4)        // 2,097,408
#define WS_DNT_OFF   (WS_GUT_OFF + NE*F2*HD*2)        // 4,456,704 ; end ~5.64 MB

__device__ __forceinline__ unsigned short f2bf(float x) {
    unsigned int u = __float_as_uint(x);
    return (unsigned short)((u + 0x7fffu + ((u >> 16) & 1u)) >> 16);
}
__device__ __forceinline__ unsigned int pk2(float a, float b) {
    unsigned int ua = __float_as_uint(a), ub = __float_as_uint(b);
    unsigned int lo = (ua + 0x7fffu + ((ua >> 16) & 1u)) >> 16;
    unsigned int hi = (ub + 0x7fffu + ((ub >> 16) & 1u)) & 0xffff0000u;
    return lo | hi;
}

// Two-level routing: per-block LDS histogram + rank, then ONE global atomic
// per (block, expert) to reserve a contiguous base. 2048 global atomics total
// instead of 131072 same-address RMWs (which cost 705 us of serialization).
__global__ void route_kernel(const int* __restrict__ ids, int* __restrict__ counts,
                             int* __restrict__ bucket) {
    __shared__ int lc[NE];   // per-block histogram
    __shared__ int lb[NE];   // per-block global base
    int tid = threadIdx.x;
    if (tid < NE) lc[tid] = 0;
    __syncthreads();

    int t = blockIdx.x * blockDim.x + tid;
    int e = ids[t];
    int rank = atomicAdd(&lc[e], 1);     // LDS atomic: fast
    __syncthreads();

    if (tid < NE) lb[tid] = atomicAdd(&counts[tid], lc[tid]);
    __syncthreads();

    bucket[e * NT + lb[e] + rank] = t;
}

// fp32 -> bf16 with transpose: guT[e][f][k] (k contig), dnT[e][h][f] (f contig)
__global__ void convert_kernel(const float* __restrict__ gu, const float* __restrict__ dn,
                               unsigned short* __restrict__ guT, unsigned short* __restrict__ dnT) {
    int idx = blockIdx.x * blockDim.x + threadIdx.x;
    if (idx < NE * F2 * HD) {
        int k = idx % HD; int r = idx / HD; int f = r % F2; int e = r / F2;
        guT[idx] = f2bf(gu[(e * HD + k) * F2 + f]);
    }
    if (idx < NE * HD * F1) {
        int f = idx % F1; int r = idx / F1; int h = r % HD; int e = r / HD;
        dnT[idx] = f2bf(dn[(e * F1 + f) * HD + h]);
    }
}

__global__ __launch_bounds__(256, 2)
void moe_kernel(const float* __restrict__ hidden, const int* __restrict__ counts,
                const int* __restrict__ bucket, const unsigned short* __restrict__ guT,
                const unsigned short* __restrict__ dnT, float* __restrict__ out)
{
    __shared__ __align__(16) unsigned char smem[41216];
    const int ACT = 8192, TOK = 40960;

    int e = blockIdx.x >> 11;        // / 2048
    int tile = blockIdx.x & 2047;
    int n_e = counts[e];
    int t0 = tile * TT;
    if (t0 >= n_e) return;

    int tid = threadIdx.x;
    int lane = tid & 63;
    int w = tid >> 6;                // wave 0..3
    int lg = lane >> 4;              // lane-group 0..3
    int l16 = lane & 15;

    if (tid < TT) {
        int idx = t0 + tid;
        if (idx >= n_e) idx = n_e - 1;          // duplicate last valid token; store-masked later
        ((int*)(smem + TOK))[tid] = bucket[e * NT + idx];
    }
    __syncthreads();

    // A-staging: thread covers row sr, 16 consecutive k at sq*16
    int sr = tid >> 2, sq = tid & 3;
    const float* srow = hidden + (size_t)(((int*)(smem + TOK))[sr]) * HD + sq * 16;
    int ss = sr & 7;
    unsigned int wb0 = (unsigned int)(sr * 128 + (((sq * 2) ^ ss) << 4));
    unsigned int wb1 = (unsigned int)(sr * 128 + (((sq * 2 + 1) ^ ss) << 4));

    // B1 per-lane byte offsets (gate cols w*48.., up cols 192+w*48.. : in-register pairing)
    const char* guTc = (const char*)(guT + (size_t)e * F2 * HD);
    unsigned int vb1[6];
    #pragma unroll
    for (int nt = 0; nt < 6; ++nt) {
        int col = (nt < 3) ? (w * 48 + nt * 16 + l16) : (192 + w * 48 + (nt - 3) * 16 + l16);
        vb1[nt] = (unsigned int)((col * HD + 8 * lg) * 2);
    }

    const f32x4 fzero = {0.f, 0.f, 0.f, 0.f};
    f32x4 acc[4][6];
    #pragma unroll
    for (int mt = 0; mt < 4; ++mt)
        #pragma unroll
        for (int nt = 0; nt < 6; ++nt) acc[mt][nt] = fzero;

    // ---------------- GEMM1: C1[64][384] over K=768, BK=64 ----------------
    #pragma unroll 1
    for (int k0 = 0; k0 < HD; k0 += 64) {
        if (k0) __syncthreads();
        {
            f32x4 v0 = *(const f32x4*)(srow + k0);
            f32x4 v1 = *(const f32x4*)(srow + k0 + 4);
            f32x4 v2 = *(const f32x4*)(srow + k0 + 8);
            f32x4 v3 = *(const f32x4*)(srow + k0 + 12);
            u32x4 lo = { pk2(v0.x, v0.y), pk2(v0.z, v0.w), pk2(v1.x, v1.y), pk2(v1.z, v1.w) };
            u32x4 hi = { pk2(v2.x, v2.y), pk2(v2.z, v2.w), pk2(v3.x, v3.y), pk2(v3.z, v3.w) };
            *(u32x4*)(smem + wb0) = lo;
            *(u32x4*)(smem + wb1) = hi;
        }
        __syncthreads();

        bf16x8 B[2][6];
        #pragma unroll
        for (int kk = 0; kk < 2; ++kk)
            #pragma unroll
            for (int nt = 0; nt < 6; ++nt)
                B[kk][nt] = *(const bf16x8*)(guTc + (vb1[nt] + (unsigned int)((k0 + kk * 32) * 2)));

        bf16x8 A[2][4];
        #pragma unroll
        for (int kk = 0; kk < 2; ++kk)
            #pragma unroll
            for (int mt = 0; mt < 4; ++mt) {
                int row = mt * 16 + l16;
                unsigned int b = (unsigned int)(row * 128 + (((kk * 4 + lg) ^ (row & 7)) << 4));
                A[kk][mt] = *(const bf16x8*)(smem + b);
            }

        #pragma unroll
        for (int kk = 0; kk < 2; ++kk)
            #pragma unroll
            for (int nt = 0; nt < 6; ++nt)
                #pragma unroll
                for (int mt = 0; mt < 4; ++mt)
                    acc[mt][nt] = __builtin_amdgcn_mfma_f32_16x16x32_bf16(A[kk][mt], B[kk][nt], acc[mt][nt], 0, 0, 0);
    }

    // ---------------- act = silu(gate)*up, in-register pairing, -> swizzled LDS ----------------
    #pragma unroll
    for (int mt = 0; mt < 4; ++mt)
        #pragma unroll
        for (int nt = 0; nt < 3; ++nt)
            #pragma unroll
            for (int p = 0; p < 4; ++p) {
                float g = acc[mt][nt][p];
                float u = acc[mt][nt + 3][p];
                float s = g / (1.f + __expf(-g));
                int row = mt * 16 + 4 * lg + p;
                int f = w * 48 + nt * 16 + l16;
                unsigned int b = (unsigned int)(ACT + row * 512 + (((f >> 3) ^ (row & 7)) << 4) + (f & 7) * 2);
                *(unsigned short*)(smem + b) = f2bf(s * u);
            }
    __syncthreads();

    // ---------------- GEMM2: out[64][768] = act[64][192] * down[192][768] ----------------
    const char* dnTc = (const char*)(dnT + (size_t)e * HD * F1);
    #pragma unroll 1
    for (int half = 0; half < 2; ++half) {
        unsigned int vb2[6];
        #pragma unroll
        for (int nt = 0; nt < 6; ++nt) {
            int h = w * 192 + half * 96 + nt * 16 + l16;
            vb2[nt] = (unsigned int)((h * F1 + 8 * lg) * 2);
        }
        f32x4 c2[4][6];
        #pragma unroll
        for (int mt = 0; mt < 4; ++mt)
            #pragma unroll
            for (int nt = 0; nt < 6; ++nt) c2[mt][nt] = fzero;

        #pragma unroll
        for (int kt = 0; kt < 6; ++kt) {
            bf16x8 A2[4];
            #pragma unroll
            for (int mt = 0; mt < 4; ++mt) {
                int row = mt * 16 + l16;
                unsigned int b = (unsigned int)(ACT + row * 512 + (((kt * 4 + lg) ^ (row & 7)) << 4));
                A2[mt] = *(const bf16x8*)(smem + b);
            }
            bf16x8 B2[6];
            #pragma unroll
            for (int nt = 0; nt < 6; ++nt)
                B2[nt] = *(const bf16x8*)(dnTc + (vb2[nt] + (unsigned int)(kt * 64)));
            #pragma unroll
            for (int nt = 0; nt < 6; ++nt)
                #pragma unroll
                for (int mt = 0; mt < 4; ++mt)
                    c2[mt][nt] = __builtin_amdgcn_mfma_f32_16x16x32_bf16(A2[mt], B2[nt], c2[mt][nt], 0, 0, 0);
        }

        int cb = w * 192 + half * 96 + l16;
        #pragma unroll
        for (int mt = 0; mt < 4; ++mt)
            #pragma unroll
            for (int p = 0; p < 4; ++p) {
                int row = mt * 16 + 4 * lg + p;
                if (t0 + row < n_e) {
                    float* orow = out + (size_t)(((int*)(smem + TOK))[row]) * HD + cb;
                    #pragma unroll
                    for (int nt = 0; nt < 6; ++nt)
                        orow[nt * 16] = c2[mt][nt][p];
                }
            }
    }
}

extern "C" void kernel_launch(void* const* d_in, const int* in_sizes, int n_in,
                              void* d_out, int out_size, void* d_ws, size_t ws_size,
                              hipStream_t stream) {
    (void)in_sizes; (void)n_in; (void)out_size; (void)ws_size;
    const float* hidden = (const float*)d_in[0];
    const int*   ids    = (const int*)d_in[1];
    const float* gu     = (const float*)d_in[2];
    const float* dn     = (const float*)d_in[3];
    float* out = (float*)d_out;

    char* ws = (char*)d_ws;
    int* counts = (int*)ws;
    int* bucket = (int*)(ws + WS_BUCKET_OFF);
    unsigned short* guT = (unsigned short*)(ws + WS_GUT_OFF);
    unsigned short* dnT = (unsigned short*)(ws + WS_DNT_OFF);

    hipMemsetAsync(d_ws, 0, 64, stream);
    route_kernel<<<NT / 256, 256, 0, stream>>>(ids, counts, bucket);
    convert_kernel<<<(NE * F2 * HD + 255) / 256, 256, 0, stream>>>(gu, dn, guT, dnT);
    moe_kernel<<<NE * TILES_PER_E, 256, 0, stream>>>(hidden, counts, bucket, guT, dnT, out);
}

// Round 3
// 297.338 us; speedup vs baseline: 3.7773x; 1.4094x over previous
//
#include <hip/hip_runtime.h>
#include <hip/hip_bf16.h>

#define NE 4
#define HD 768
#define F2 384
#define F1 192
#define NT 131072
#define TT 128
#define TPE 1024   // tiles per expert = NT/TT

typedef __attribute__((ext_vector_type(8))) short bf16x8;
typedef __attribute__((ext_vector_type(4))) float f32x4;
typedef __attribute__((ext_vector_type(4))) unsigned int u32x4;

// LDS byte offsets (dynamic shared, 147968 B total)
#define LA0 0u
#define LA1 16384u
#define LB0 32768u
#define LB1 81920u
#define LACT 0u        // overlays A0/A1/B0-head after GEMM1
#define LC0 49152u     // B2 buf0, overlays B0-tail/B1-head
#define LC1 98304u     // B2 buf1
#define LTOK 147456u
#define SMEM_BYTES 147968

// workspace layout (bytes)
#define WS_BUCKET_OFF 256
#define WS_GUT_OFF   (WS_BUCKET_OFF + NE*NT*4)
#define WS_DNT_OFF   (WS_GUT_OFF + NE*F2*HD*2)

__device__ __forceinline__ unsigned short f2bf(float x) {
    unsigned int u = __float_as_uint(x);
    return (unsigned short)((u + 0x7fffu + ((u >> 16) & 1u)) >> 16);
}
__device__ __forceinline__ unsigned int pk2(float a, float b) {
    unsigned int ua = __float_as_uint(a), ub = __float_as_uint(b);
    unsigned int lo = (ua + 0x7fffu + ((ua >> 16) & 1u)) >> 16;
    unsigned int hi = (ub + 0x7fffu + ((ub >> 16) & 1u)) & 0xffff0000u;
    return lo | hi;
}

__global__ void route_kernel(const int* __restrict__ ids, int* __restrict__ counts,
                             int* __restrict__ bucket) {
    __shared__ int lc[NE];
    __shared__ int lb[NE];
    int tid = threadIdx.x;
    if (tid < NE) lc[tid] = 0;
    __syncthreads();
    int t = blockIdx.x * blockDim.x + tid;
    int e = ids[t];
    int rank = atomicAdd(&lc[e], 1);
    __syncthreads();
    if (tid < NE) lb[tid] = atomicAdd(&counts[tid], lc[tid]);
    __syncthreads();
    bucket[e * NT + lb[e] + rank] = t;
}

// fp32 -> bf16 with transpose: guT[e][f][k] (k contig), dnT[e][h][f] (f contig)
__global__ void convert_kernel(const float* __restrict__ gu, const float* __restrict__ dn,
                               unsigned short* __restrict__ guT, unsigned short* __restrict__ dnT) {
    int idx = blockIdx.x * blockDim.x + threadIdx.x;
    if (idx < NE * F2 * HD) {
        int k = idx % HD; int r = idx / HD; int f = r % F2; int e = r / F2;
        guT[idx] = f2bf(gu[(e * HD + k) * F2 + f]);
    }
    if (idx < NE * HD * F1) {
        int f = idx % F1; int r = idx / F1; int h = r % HD; int e = r / HD;
        dnT[idx] = f2bf(dn[(e * F1 + f) * HD + h]);
    }
}

__global__ __launch_bounds__(512, 1)
void moe_kernel(const float* __restrict__ hidden, const int* __restrict__ counts,
                const int* __restrict__ bucket, const unsigned short* __restrict__ guT,
                const unsigned short* __restrict__ dnT, float* __restrict__ out)
{
    extern __shared__ __align__(16) unsigned char smem[];

    int e = blockIdx.x >> 10;
    int tile = blockIdx.x & (TPE - 1);
    int n_e = counts[e];
    int t0 = tile * TT;
    if (t0 >= n_e) return;

    int tid = threadIdx.x;
    int lane = tid & 63;
    int w = tid >> 6;
    int rw64 = (w >> 2) << 6;      // row half: 0 or 64
    int w2 = w & 3;                // col quarter
    int lg = lane >> 4;
    int l16 = lane & 15;
    int l7 = l16 & 7;

    int* tokp = (int*)(smem + LTOK);
    if (tid < TT) {
        int idx = t0 + tid; if (idx >= n_e) idx = n_e - 1;
        tokp[tid] = bucket[e * NT + idx];
    }
    __syncthreads();

    // ---- staging identities ----
    int arow = tid >> 2, kq = tid & 3;              // A: 128 rows x 4 k-quarters
    const float* ab = hidden + (size_t)tokp[arow] * HD;
    int colb = tid >> 3, ks = tid & 7;              // B: chunk col/k-slot base
    const unsigned short* guTe = guT + (size_t)e * F2 * HD;
    const unsigned short* dnTe = dnT + (size_t)e * HD * F1;

    unsigned awb0 = (unsigned)(arow * 128 + ((kq ^ (arow & 7)) << 4));        // kslot=kq
    unsigned awb1 = (unsigned)(arow * 128 + (((4 + kq) ^ (arow & 7)) << 4));  // kslot=4+kq
    unsigned bwb  = (unsigned)(colb * 128 + ((ks ^ (colb & 7)) << 4));

    f32x4 av0, av1, av2, av3;
    bf16x8 bv[6];

    auto issueA = [&](int k0) {
        const float* p = ab + k0 + kq * 8;
        av0 = *(const f32x4*)p;          av1 = *(const f32x4*)(p + 4);
        av2 = *(const f32x4*)(p + 32);   av3 = *(const f32x4*)(p + 36);
    };
    auto writeA = [&](unsigned base) {
        u32x4 lo = {pk2(av0.x,av0.y), pk2(av0.z,av0.w), pk2(av1.x,av1.y), pk2(av1.z,av1.w)};
        u32x4 hi = {pk2(av2.x,av2.y), pk2(av2.z,av2.w), pk2(av3.x,av3.y), pk2(av3.z,av3.w)};
        *(u32x4*)(smem + base + awb0) = lo;
        *(u32x4*)(smem + base + awb1) = hi;
    };
    auto issueB = [&](int k0) {
        #pragma unroll
        for (int jj = 0; jj < 6; ++jj)
            bv[jj] = *(const bf16x8*)(guTe + (size_t)(colb + jj * 64) * HD + k0 + ks * 8);
    };
    auto issueB2 = [&](int half, int s) {
        #pragma unroll
        for (int jj = 0; jj < 6; ++jj)
            bv[jj] = *(const bf16x8*)(dnTe + (size_t)(half * F2 + colb + jj * 64) * F1 + s * 64 + ks * 8);
    };
    auto writeB = [&](unsigned base) {
        #pragma unroll
        for (int jj = 0; jj < 6; ++jj)
            *(bf16x8*)(smem + base + bwb + jj * 8192u) = bv[jj];
    };

    // ---- frag read bases ----
    unsigned arb[4], brb1[6], b2rb[6], a2rb[4];
    #pragma unroll
    for (int mt = 0; mt < 4; ++mt) {
        arb[mt] = (unsigned)((rw64 + mt * 16 + l16) * 128);
        a2rb[mt] = (unsigned)(LACT + (rw64 + mt * 16 + l16) * 384);
    }
    #pragma unroll
    for (int nt = 0; nt < 6; ++nt) {
        int col = w2 * 48 + (nt < 3 ? nt * 16 : 192 + (nt - 3) * 16) + l16;
        brb1[nt] = (unsigned)(col * 128);
        b2rb[nt] = (unsigned)((w2 * 96 + nt * 16 + l16) * 128);
    }
    unsigned xk0 = (unsigned)((lg ^ l7) << 4);
    unsigned xk1 = (unsigned)(((4 + lg) ^ l7) << 4);

    const f32x4 fzero = {0.f, 0.f, 0.f, 0.f};
    f32x4 acc[4][6];
    #pragma unroll
    for (int mt = 0; mt < 4; ++mt)
        #pragma unroll
        for (int nt = 0; nt < 6; ++nt) acc[mt][nt] = fzero;

    // ================= GEMM1: C1[128][384], K=768, BK=64, pipelined =================
    issueA(0); issueB(0);
    writeA(LA0); writeB(LB0);
    __syncthreads();

    #pragma unroll 1
    for (int t = 0; t < 12; ++t) {
        unsigned Ab  = (t & 1) ? LA1 : LA0;
        unsigned Bb  = (t & 1) ? LB1 : LB0;
        unsigned Abn = (t & 1) ? LA0 : LA1;
        unsigned Bbn = (t & 1) ? LB0 : LB1;
        if (t < 11) { issueA((t + 1) * 64); issueB((t + 1) * 64); }

        bf16x8 Af[2][4], Bf[2][6];
        #pragma unroll
        for (int mt = 0; mt < 4; ++mt) {
            Af[0][mt] = *(const bf16x8*)(smem + Ab + arb[mt] + xk0);
            Af[1][mt] = *(const bf16x8*)(smem + Ab + arb[mt] + xk1);
        }
        #pragma unroll
        for (int nt = 0; nt < 6; ++nt) {
            Bf[0][nt] = *(const bf16x8*)(smem + Bb + brb1[nt] + xk0);
            Bf[1][nt] = *(const bf16x8*)(smem + Bb + brb1[nt] + xk1);
        }
        #pragma unroll
        for (int kk = 0; kk < 2; ++kk)
            #pragma unroll
            for (int nt = 0; nt < 6; ++nt)
                #pragma unroll
                for (int mt = 0; mt < 4; ++mt)
                    acc[mt][nt] = __builtin_amdgcn_mfma_f32_16x16x32_bf16(Af[kk][mt], Bf[kk][nt], acc[mt][nt], 0, 0, 0);

        if (t < 11) { writeA(Abn); writeB(Bbn); }
        __syncthreads();
    }

    // ================= act = silu(gate)*up -> LDS; prefetch B2(0,0) =================
    issueB2(0, 0);
    #pragma unroll
    for (int mt = 0; mt < 4; ++mt)
        #pragma unroll
        for (int nt = 0; nt < 3; ++nt)
            #pragma unroll
            for (int p = 0; p < 4; ++p) {
                float g = acc[mt][nt][p];
                float u = acc[mt][nt + 3][p];
                float s = g / (1.f + __expf(-g));
                int row = rw64 + mt * 16 + 4 * lg + p;
                int f = w2 * 48 + nt * 16 + l16;
                unsigned b = (unsigned)(LACT + row * 384 + (((f >> 3) ^ (row & 7)) << 4) + (f & 7) * 2);
                *(unsigned short*)(smem + b) = f2bf(s * u);
            }
    writeB(LC0);
    __syncthreads();

    // token ids for stores (rows identical across halves)
    int strow[4][4];
    #pragma unroll
    for (int mt = 0; mt < 4; ++mt)
        #pragma unroll
        for (int p = 0; p < 4; ++p)
            strow[mt][p] = tokp[rw64 + mt * 16 + 4 * lg + p];

    // ================= GEMM2: out[128][768] = act[128][192] * down =================
    #pragma unroll 1
    for (int half = 0; half < 2; ++half) {
        f32x4 c2[4][6];
        #pragma unroll
        for (int mt = 0; mt < 4; ++mt)
            #pragma unroll
            for (int nt = 0; nt < 6; ++nt) c2[mt][nt] = fzero;

        #pragma unroll
        for (int s = 0; s < 3; ++s) {
            unsigned Cb  = ((half + s) & 1) ? LC1 : LC0;
            unsigned Cbn = ((half + s) & 1) ? LC0 : LC1;
            int do_next = (s < 2) || (half == 0);
            if (s < 2) issueB2(half, s + 1);
            else if (half == 0) issueB2(1, 0);

            bf16x8 A2[2][4], B2f[2][6];
            #pragma unroll
            for (int mt = 0; mt < 4; ++mt) {
                A2[0][mt] = *(const bf16x8*)(smem + a2rb[mt] + s * 128 + xk0);
                A2[1][mt] = *(const bf16x8*)(smem + a2rb[mt] + s * 128 + xk1);
            }
            #pragma unroll
            for (int nt = 0; nt < 6; ++nt) {
                B2f[0][nt] = *(const bf16x8*)(smem + Cb + b2rb[nt] + xk0);
                B2f[1][nt] = *(const bf16x8*)(smem + Cb + b2rb[nt] + xk1);
            }
            #pragma unroll
            for (int kk = 0; kk < 2; ++kk)
                #pragma unroll
                for (int nt = 0; nt < 6; ++nt)
                    #pragma unroll
                    for (int mt = 0; mt < 4; ++mt)
                        c2[mt][nt] = __builtin_amdgcn_mfma_f32_16x16x32_bf16(A2[kk][mt], B2f[kk][nt], c2[mt][nt], 0, 0, 0);

            if (do_next) {
                writeB(Cbn);
                __syncthreads();
            }
        }

        #pragma unroll
        for (int mt = 0; mt < 4; ++mt)
            #pragma unroll
            for (int p = 0; p < 4; ++p) {
                int rl = rw64 + mt * 16 + 4 * lg + p;
                if (t0 + rl < n_e) {
                    float* orow = out + (size_t)strow[mt][p] * HD + half * F2 + w2 * 96 + l16;
                    #pragma unroll
                    for (int nt = 0; nt < 6; ++nt)
                        orow[nt * 16] = c2[mt][nt][p];
                }
            }
    }
}

extern "C" void kernel_launch(void* const* d_in, const int* in_sizes, int n_in,
                              void* d_out, int out_size, void* d_ws, size_t ws_size,
                              hipStream_t stream) {
    (void)in_sizes; (void)n_in; (void)out_size; (void)ws_size;
    const float* hidden = (const float*)d_in[0];
    const int*   ids    = (const int*)d_in[1];
    const float* gu     = (const float*)d_in[2];
    const float* dn     = (const float*)d_in[3];
    float* out = (float*)d_out;

    char* ws = (char*)d_ws;
    int* counts = (int*)ws;
    int* bucket = (int*)(ws + WS_BUCKET_OFF);
    unsigned short* guT = (unsigned short*)(ws + WS_GUT_OFF);
    unsigned short* dnT = (unsigned short*)(ws + WS_DNT_OFF);

    hipMemsetAsync(d_ws, 0, 64, stream);
    route_kernel<<<NT / 256, 256, 0, stream>>>(ids, counts, bucket);
    convert_kernel<<<(NE * F2 * HD + 255) / 256, 256, 0, stream>>>(gu, dn, guT, dnT);
    moe_kernel<<<NE * TPE, 512, SMEM_BYTES, stream>>>(hidden, counts, bucket, guT, dnT, out);
}